// Round 2
// baseline (756.285 us; speedup 1.0000x reference)
//
#include <hip/hip_runtime.h>
#include <math.h>

#define TEMP_INV 10.0f
#define MASKV -1.0f
#define EPSV 1e-12f

__device__ __forceinline__ void gload16(const void* g, void* l) {
  __builtin_amdgcn_global_load_lds(
      (const __attribute__((address_space(1))) void*)g,
      (__attribute__((address_space(3))) void*)l, 16, 0, 0);
}

__device__ __forceinline__ float wmax(float v) {
#pragma unroll
  for (int m = 1; m < 64; m <<= 1) v = fmaxf(v, __shfl_xor(v, m));
  return v;
}
__device__ __forceinline__ float wsum(float v) {
#pragma unroll
  for (int m = 1; m < 64; m <<= 1) v += __shfl_xor(v, m);
  return v;
}

#define DOT4(accv, Av, Bv)            \
  accv = fmaf(Av.x, Bv.x, accv);      \
  accv = fmaf(Av.y, Bv.y, accv);      \
  accv = fmaf(Av.z, Bv.z, accv);      \
  accv = fmaf(Av.w, Bv.w, accv);

// ---------------------------------------------------------------------------
// Kernel 1: h = relu(imgs@W1+b1); unc = sigmoid(h@W2+b2); img row norms
// ---------------------------------------------------------------------------
__global__ __launch_bounds__(256) void k_prep(
    const float* __restrict__ imgs, const float* __restrict__ W1,
    const float* __restrict__ b1, const float* __restrict__ W2,
    const float* __restrict__ b2, float* __restrict__ unc,
    float* __restrict__ nrm) {
  int i = blockIdx.y;
  int r0 = blockIdx.x * 4;
  int t = threadIdx.x, lane = t & 63, wv = t >> 6;
  __shared__ __align__(16) float im[4][512];
  __shared__ float part[8][4];

  for (int q = t; q < 512; q += 256) {
    int rr = q >> 7;
    int dq = (q & 127) << 2;
    *(float4*)&im[rr][dq] = *(const float4*)&imgs[(i * 36 + r0 + rr) * 512 + dq];
  }
  __syncthreads();

  float a0 = 0.f, a1 = 0.f, a2 = 0.f, a3 = 0.f;
  for (int d = 0; d < 512; ++d) {
    float w = W1[d * 256 + t];
    a0 = fmaf(im[0][d], w, a0);
    a1 = fmaf(im[1][d], w, a1);
    a2 = fmaf(im[2][d], w, a2);
    a3 = fmaf(im[3][d], w, a3);
  }
  float bb = b1[t], w2 = W2[t];
  float v[4];
  v[0] = fmaxf(a0 + bb, 0.f) * w2;
  v[1] = fmaxf(a1 + bb, 0.f) * w2;
  v[2] = fmaxf(a2 + bb, 0.f) * w2;
  v[3] = fmaxf(a3 + bb, 0.f) * w2;
  float n[4];
#pragma unroll
  for (int p = 0; p < 4; ++p) {
    float x0 = im[p][t], x1 = im[p][t + 256];
    n[p] = x0 * x0 + x1 * x1;
  }
#pragma unroll
  for (int m = 1; m < 64; m <<= 1) {
#pragma unroll
    for (int p = 0; p < 4; ++p) {
      v[p] += __shfl_xor(v[p], m);
      n[p] += __shfl_xor(n[p], m);
    }
  }
  if (lane == 0) {
#pragma unroll
    for (int p = 0; p < 4; ++p) {
      part[p][wv] = v[p];
      part[4 + p][wv] = n[p];
    }
  }
  __syncthreads();
  if (t < 8) {
    float s = part[t][0] + part[t][1] + part[t][2] + part[t][3];
    if (t < 4)
      unc[i * 36 + r0 + t] = 1.f / (1.f + __expf(-(s + b2[0])));
    else
      nrm[i * 36 + r0 + (t - 4)] = sqrtf(s);
  }
}

// ---------------------------------------------------------------------------
// Kernel 2: Gram matrices G[j][w][w'] = caps[j,w].caps[j,w']
// grid (2 halves, 64 j), 128 threads; swizzled row-major LDS, 4x4 reg tiles
// ---------------------------------------------------------------------------
__global__ __launch_bounds__(128) void k_gram(const float* __restrict__ caps,
                                              float* __restrict__ G) {
  int j = blockIdx.y, h = blockIdx.x;
  int t = threadIdx.x;
  __shared__ __align__(16) float cs[52 * 128];

  int rg = t / 13, wg = t - rg * 13;
  bool act = (t < 91);
  int r0 = h * 24 + 4 * rg;  // h0: 0..27, h1: 24..51
  int w0 = 4 * wg;           // 0..51
  int fa = (r0 >> 2) & 7;
  int fb = wg & 7;
  float acc[4][4] = {};

  for (int ch = 0; ch < 4; ++ch) {
    int d0 = ch * 128;
    // stage 52 rows x 128 floats, swizzled: pos_chunk = c ^ ((row>>2)&7)
    for (int ps = 0; ps < 13; ++ps) {
      int row = ps * 4 + (t >> 5);
      int c = t & 31;
      int grow = row > 49 ? 49 : row;
      float4 v = *(const float4*)&caps[(j * 50 + grow) * 512 + d0 + c * 4];
      *(float4*)&cs[row * 128 + ((c ^ (ps & 7)) << 2)] = v;
    }
    __syncthreads();
    if (act) {
      const float* aB = &cs[r0 * 128];
      const float* bB = &cs[w0 * 128];
#pragma unroll
      for (int q = 0; q < 32; ++q) {
        int pa = ((q ^ fa) << 2), pb = ((q ^ fb) << 2);
        float4 A0 = *(const float4*)(aB + pa);
        float4 A1 = *(const float4*)(aB + 128 + pa);
        float4 A2 = *(const float4*)(aB + 256 + pa);
        float4 A3 = *(const float4*)(aB + 384 + pa);
        float4 B0 = *(const float4*)(bB + pb);
        float4 B1 = *(const float4*)(bB + 128 + pb);
        float4 B2 = *(const float4*)(bB + 256 + pb);
        float4 B3 = *(const float4*)(bB + 384 + pb);
        DOT4(acc[0][0], A0, B0) DOT4(acc[0][1], A0, B1)
        DOT4(acc[0][2], A0, B2) DOT4(acc[0][3], A0, B3)
        DOT4(acc[1][0], A1, B0) DOT4(acc[1][1], A1, B1)
        DOT4(acc[1][2], A1, B2) DOT4(acc[1][3], A1, B3)
        DOT4(acc[2][0], A2, B0) DOT4(acc[2][1], A2, B1)
        DOT4(acc[2][2], A2, B2) DOT4(acc[2][3], A2, B3)
        DOT4(acc[3][0], A3, B0) DOT4(acc[3][1], A3, B1)
        DOT4(acc[3][2], A3, B2) DOT4(acc[3][3], A3, B3)
      }
    }
    __syncthreads();
  }
  if (act) {
#pragma unroll
    for (int p = 0; p < 4; ++p) {
      int w = r0 + p;
      if (w < 50) {
#pragma unroll
        for (int qq = 0; qq < 4; ++qq) {
          int wp = w0 + qq;
          if (wp < 50) G[j * 2500 + w * 50 + wp] = acc[p][qq];
        }
      }
    }
  }
}

// ---------------------------------------------------------------------------
// Kernel 3: main — per (i,j): sims GEMM (producer/consumer waves, swizzled
// LDS, global_load_lds dbuf) + attention epilogue + quadratic-form norm
// ---------------------------------------------------------------------------
__global__ __launch_bounds__(256, 4) void k_main(
    const float* __restrict__ imgs, const float* __restrict__ caps,
    const int* __restrict__ img_lens, const int* __restrict__ cap_lens,
    const float* __restrict__ unc, const float* __restrict__ nrm,
    const float* __restrict__ G, float* __restrict__ out) {
  __shared__ __align__(16) float a_s[2][36 * 64];
  __shared__ __align__(16) float b_s[2][52 * 64];
  __shared__ __align__(16) float sim_s[36 * 52 + 16];

  int bid = blockIdx.x;
  int g = bid >> 6, u = bid & 63;
  int i = ((g >> 3) << 3) | (u & 7);
  int j = ((g & 7) << 3) | (u >> 3);
  int t = threadIdx.x, lane = t & 63, wv = t >> 6;

  const float* aG = imgs + i * 36 * 512;
  const float* bG = caps + j * 50 * 512;

  int rg = t / 13, wg = t - rg * 13;
  bool act = (t < 117);  // waves 0,1 compute
  int fa = rg & 7, fb = wg & 7;
  float acc[4][4] = {};

  int rr = lane >> 4, cc = lane & 15;
  // prologue: stage chunk 0 into buffer 0 (producers: waves 2,3)
  if (wv == 2) {
#pragma unroll
    for (int L = 0; L < 9; ++L)
      gload16(aG + (4 * L + rr) * 512 + ((cc ^ (L & 7)) << 2), &a_s[0][L * 256]);
  } else if (wv == 3) {
#pragma unroll
    for (int L = 0; L < 13; ++L) {
      int row = 4 * L + rr;
      row = row > 49 ? 49 : row;
      gload16(bG + row * 512 + ((cc ^ (L & 7)) << 2), &b_s[0][L * 256]);
    }
  }
  __syncthreads();

  for (int c8 = 0; c8 < 8; ++c8) {
    int cur = c8 & 1;
    if (c8 < 7) {
      int d0 = (c8 + 1) * 64, nb = cur ^ 1;
      if (wv == 2) {
#pragma unroll
        for (int L = 0; L < 9; ++L)
          gload16(aG + (4 * L + rr) * 512 + d0 + ((cc ^ (L & 7)) << 2),
                  &a_s[nb][L * 256]);
      } else if (wv == 3) {
#pragma unroll
        for (int L = 0; L < 13; ++L) {
          int row = 4 * L + rr;
          row = row > 49 ? 49 : row;
          gload16(bG + row * 512 + d0 + ((cc ^ (L & 7)) << 2),
                  &b_s[nb][L * 256]);
        }
      }
    }
    if (act) {
      const float* aB = &a_s[cur][rg * 256];
      const float* bB = &b_s[cur][wg * 256];
#pragma unroll
      for (int q = 0; q < 16; ++q) {
        int pa = ((q ^ fa) << 2), pb = ((q ^ fb) << 2);
        float4 A0 = *(const float4*)(aB + pa);
        float4 A1 = *(const float4*)(aB + 64 + pa);
        float4 A2 = *(const float4*)(aB + 128 + pa);
        float4 A3 = *(const float4*)(aB + 192 + pa);
        float4 B0 = *(const float4*)(bB + pb);
        float4 B1 = *(const float4*)(bB + 64 + pb);
        float4 B2 = *(const float4*)(bB + 128 + pb);
        float4 B3 = *(const float4*)(bB + 192 + pb);
        DOT4(acc[0][0], A0, B0) DOT4(acc[0][1], A0, B1)
        DOT4(acc[0][2], A0, B2) DOT4(acc[0][3], A0, B3)
        DOT4(acc[1][0], A1, B0) DOT4(acc[1][1], A1, B1)
        DOT4(acc[1][2], A1, B2) DOT4(acc[1][3], A1, B3)
        DOT4(acc[2][0], A2, B0) DOT4(acc[2][1], A2, B1)
        DOT4(acc[2][2], A2, B2) DOT4(acc[2][3], A2, B3)
        DOT4(acc[3][0], A3, B0) DOT4(acc[3][1], A3, B1)
        DOT4(acc[3][2], A3, B2) DOT4(acc[3][3], A3, B3)
      }
    }
    __syncthreads();
  }

  // write sims (compute waves) | stage G stride-51 into b_s[0] (producers)
  if (act) {
#pragma unroll
    for (int p = 0; p < 4; ++p) {
      float4 v = make_float4(acc[p][0], acc[p][1], acc[p][2], acc[p][3]);
      *(float4*)&sim_s[(rg * 4 + p) * 52 + wg * 4] = v;
    }
  }
  float* g_s = &b_s[0][0];
  if (wv >= 2) {
    for (int q = t - 128; q < 2500; q += 128) {
      int w = q / 50, ww = q - w * 50;
      g_s[w * 51 + ww] = G[j * 2500 + q];
    }
  }
  __syncthreads();

  // ---- epilogue: each wave owns rows [wv*9, wv*9+9) ----
  int ilen = img_lens[i];
  int cl = cap_lens[j];
  cl = cl > 50 ? 50 : cl;
  int r0e = wv * 9;
  float num9[9];

#pragma unroll
  for (int k = 0; k < 9; ++k) {
    int r = r0e + k;
    float s = (lane < 52) ? sim_s[r * 52 + lane] : 0.f;
    bool valid = lane < cl;
    float sv = valid ? s : -INFINITY;
    float m = wmax(sv);
    unsigned long long bal = __ballot(valid && (sv == m));
    int fl = (int)__ffsll(bal) - 1;  // first (lowest-index) argmax
    float e = valid ? __expf((sv - m) * TEMP_INV) : 0.f;
    float dn = wsum(e);
    float alpha = unc[i * 36 + r];
    float p = alpha * e / dn;
    if (m > MASKV && lane == fl) p += (1.f - alpha);
    num9[k] = wsum(valid ? p * s : 0.f);
    if (lane < 52) sim_s[r * 52 + lane] = p;  // overwrite sims with weights
  }

  // quadratic form (G p) per row, lane = w'; G reads amortized over 9 rows
  float acc9[9] = {};
  for (int ww = 0; ww < 52; ww += 4) {
    float g0 = g_s[lane * 51 + ww + 0];
    float g1 = g_s[lane * 51 + ww + 1];
    float g2 = g_s[lane * 51 + ww + 2];
    float g3 = g_s[lane * 51 + ww + 3];
#pragma unroll
    for (int k = 0; k < 9; ++k) {
      float4 p4 = *(const float4*)&sim_s[(r0e + k) * 52 + ww];
      acc9[k] = fmaf(p4.x, g0, acc9[k]);
      acc9[k] = fmaf(p4.y, g1, acc9[k]);
      acc9[k] = fmaf(p4.z, g2, acc9[k]);
      acc9[k] = fmaf(p4.w, g3, acc9[k]);
    }
  }
#pragma unroll
  for (int k = 0; k < 9; ++k) {
    int r = r0e + k;
    float pown = (lane < 50) ? sim_s[r * 52 + lane] : 0.f;
    float qd = wsum(pown * acc9[k]);
    if (lane == 0) {
      float res;
      if (r < ilen) {
        float ni = fmaxf(nrm[i * 36 + r], EPSV);
        float nw = fmaxf(sqrtf(qd), EPSV);
        res = num9[k] / (ni * nw);
      } else {
        res = MASKV;
      }
      out[(i * 64 + j) * 36 + r] = res;
    }
  }
}

extern "C" void kernel_launch(void* const* d_in, const int* in_sizes, int n_in,
                              void* d_out, int out_size, void* d_ws,
                              size_t ws_size, hipStream_t stream) {
  const float* imgs = (const float*)d_in[0];
  const float* caps = (const float*)d_in[1];
  const int* img_lens = (const int*)d_in[2];
  const int* cap_lens = (const int*)d_in[3];
  const float* W1 = (const float*)d_in[4];
  const float* b1 = (const float*)d_in[5];
  const float* W2 = (const float*)d_in[6];
  const float* b2 = (const float*)d_in[7];
  float* out = (float*)d_out;
  float* ws = (float*)d_ws;
  float* unc = ws;          // 2304 floats
  float* nrm = ws + 2304;   // 2304 floats
  float* G = ws + 4608;     // 64*2500 floats

  hipLaunchKernelGGL(k_prep, dim3(9, 64), dim3(256), 0, stream, imgs, W1, b1,
                     W2, b2, unc, nrm);
  hipLaunchKernelGGL(k_gram, dim3(2, 64), dim3(128), 0, stream, caps, G);
  hipLaunchKernelGGL(k_main, dim3(4096), dim3(256), 0, stream, imgs, caps,
                     img_lens, cap_lens, unc, nrm, G, out);
}

// Round 4
// 308.364 us; speedup vs baseline: 2.4526x; 2.4526x over previous
//
#include <hip/hip_runtime.h>
#include <math.h>

#define TEMP_INV 10.0f
#define MASKV -1.0f
#define EPSV 1e-12f

__device__ __forceinline__ void gload16(const void* g, void* l) {
  __builtin_amdgcn_global_load_lds(
      (const __attribute__((address_space(1))) void*)g,
      (__attribute__((address_space(3))) void*)l, 16, 0, 0);
}

__device__ __forceinline__ float wmax(float v) {
#pragma unroll
  for (int m = 1; m < 64; m <<= 1) v = fmaxf(v, __shfl_xor(v, m));
  return v;
}
__device__ __forceinline__ float wsum(float v) {
#pragma unroll
  for (int m = 1; m < 64; m <<= 1) v += __shfl_xor(v, m);
  return v;
}

#define DOT4(accv, Av, Bv)       \
  accv = fmaf(Av.x, Bv.x, accv); \
  accv = fmaf(Av.y, Bv.y, accv); \
  accv = fmaf(Av.z, Bv.z, accv); \
  accv = fmaf(Av.w, Bv.w, accv);

// ---------------------------------------------------------------------------
// Kernel 1: h = relu(imgs@W1+b1); unc = sigmoid(h@W2+b2); img row norms
// ---------------------------------------------------------------------------
__global__ __launch_bounds__(256) void k_prep(
    const float* __restrict__ imgs, const float* __restrict__ W1,
    const float* __restrict__ b1, const float* __restrict__ W2,
    const float* __restrict__ b2, float* __restrict__ unc,
    float* __restrict__ nrm) {
  int i = blockIdx.y;
  int r0 = blockIdx.x * 4;
  int t = threadIdx.x, lane = t & 63, wv = t >> 6;
  __shared__ __align__(16) float im[4][512];
  __shared__ float part[8][4];

  for (int q = t; q < 512; q += 256) {
    int rr = q >> 7;
    int dq = (q & 127) << 2;
    *(float4*)&im[rr][dq] = *(const float4*)&imgs[(i * 36 + r0 + rr) * 512 + dq];
  }
  __syncthreads();

  float a0 = 0.f, a1 = 0.f, a2 = 0.f, a3 = 0.f;
  for (int d = 0; d < 512; ++d) {
    float w = W1[d * 256 + t];
    a0 = fmaf(im[0][d], w, a0);
    a1 = fmaf(im[1][d], w, a1);
    a2 = fmaf(im[2][d], w, a2);
    a3 = fmaf(im[3][d], w, a3);
  }
  float bb = b1[t], w2 = W2[t];
  float v[4];
  v[0] = fmaxf(a0 + bb, 0.f) * w2;
  v[1] = fmaxf(a1 + bb, 0.f) * w2;
  v[2] = fmaxf(a2 + bb, 0.f) * w2;
  v[3] = fmaxf(a3 + bb, 0.f) * w2;
  float n[4];
#pragma unroll
  for (int p = 0; p < 4; ++p) {
    float x0 = im[p][t], x1 = im[p][t + 256];
    n[p] = x0 * x0 + x1 * x1;
  }
#pragma unroll
  for (int m = 1; m < 64; m <<= 1) {
#pragma unroll
    for (int p = 0; p < 4; ++p) {
      v[p] += __shfl_xor(v[p], m);
      n[p] += __shfl_xor(n[p], m);
    }
  }
  if (lane == 0) {
#pragma unroll
    for (int p = 0; p < 4; ++p) {
      part[p][wv] = v[p];
      part[4 + p][wv] = n[p];
    }
  }
  __syncthreads();
  if (t < 8) {
    float s = part[t][0] + part[t][1] + part[t][2] + part[t][3];
    if (t < 4)
      unc[i * 36 + r0 + t] = 1.f / (1.f + __expf(-(s + b2[0])));
    else
      nrm[i * 36 + r0 + (t - 4)] = sqrtf(s);
  }
}

// ---------------------------------------------------------------------------
// Kernel 2: Gram matrices G[j][w][w'] = caps[j,w].caps[j,w'] (row-major 50)
// ---------------------------------------------------------------------------
__global__ __launch_bounds__(128) void k_gram(const float* __restrict__ caps,
                                              float* __restrict__ G) {
  int j = blockIdx.y, h = blockIdx.x;
  int t = threadIdx.x;
  __shared__ __align__(16) float cs[52 * 128];

  int rg = t / 13, wg = t - rg * 13;
  bool act = (t < 91);
  int r0 = h * 24 + 4 * rg;
  int w0 = 4 * wg;
  int fa = (r0 >> 2) & 7;
  int fb = wg & 7;
  float acc[4][4] = {};

  for (int ch = 0; ch < 4; ++ch) {
    int d0 = ch * 128;
    for (int ps = 0; ps < 13; ++ps) {
      int row = ps * 4 + (t >> 5);
      int c = t & 31;
      int grow = row > 49 ? 49 : row;
      float4 v = *(const float4*)&caps[(j * 50 + grow) * 512 + d0 + c * 4];
      *(float4*)&cs[row * 128 + ((c ^ (ps & 7)) << 2)] = v;
    }
    __syncthreads();
    if (act) {
      const float* aB = &cs[r0 * 128];
      const float* bB = &cs[w0 * 128];
#pragma unroll
      for (int q = 0; q < 32; ++q) {
        int pa = ((q ^ fa) << 2), pb = ((q ^ fb) << 2);
        float4 A0 = *(const float4*)(aB + pa);
        float4 A1 = *(const float4*)(aB + 128 + pa);
        float4 A2 = *(const float4*)(aB + 256 + pa);
        float4 A3 = *(const float4*)(aB + 384 + pa);
        float4 B0 = *(const float4*)(bB + pb);
        float4 B1 = *(const float4*)(bB + 128 + pb);
        float4 B2 = *(const float4*)(bB + 256 + pb);
        float4 B3 = *(const float4*)(bB + 384 + pb);
        DOT4(acc[0][0], A0, B0) DOT4(acc[0][1], A0, B1)
        DOT4(acc[0][2], A0, B2) DOT4(acc[0][3], A0, B3)
        DOT4(acc[1][0], A1, B0) DOT4(acc[1][1], A1, B1)
        DOT4(acc[1][2], A1, B2) DOT4(acc[1][3], A1, B3)
        DOT4(acc[2][0], A2, B0) DOT4(acc[2][1], A2, B1)
        DOT4(acc[2][2], A2, B2) DOT4(acc[2][3], A2, B3)
        DOT4(acc[3][0], A3, B0) DOT4(acc[3][1], A3, B1)
        DOT4(acc[3][2], A3, B2) DOT4(acc[3][3], A3, B3)
      }
    }
    __syncthreads();
  }
  if (act) {
#pragma unroll
    for (int p = 0; p < 4; ++p) {
      int w = r0 + p;
      if (w < 50) {
#pragma unroll
        for (int qq = 0; qq < 4; ++qq) {
          int wp = w0 + qq;
          if (wp < 50) G[j * 2500 + w * 50 + wp] = acc[p][qq];
        }
      }
    }
  }
}

// ---------------------------------------------------------------------------
// Kernel 3: sims GEMM  M=2304 (i,r) x N=3200 (j,w) x K=512, NT fp32.
// 128x128 block tile, 8x8 per-thread, kc=32 double-buffered global_load_lds,
// XOR swizzle chunk ^= (row>>3)&7 within 32-float rows.
// ---------------------------------------------------------------------------
__global__ __launch_bounds__(256, 2) void k_sims(const float* __restrict__ imgs,
                                                 const float* __restrict__ caps,
                                                 float* __restrict__ sims) {
  __shared__ __align__(16) float a_s[2][128 * 32];
  __shared__ __align__(16) float b_s[2][128 * 32];
  int bid = blockIdx.x;
  int bm = bid / 25, bn = bid - bm * 25;
  const float* A = imgs + bm * 128 * 512;
  const float* B = caps + bn * 128 * 512;
  int t = threadIdx.x, lane = t & 63, wv = t >> 6;
  int ty = t >> 4, tx = t & 15;

  int srow = lane >> 3;  // row-within-inst (0..7)
  int cp = lane & 7;     // chunk slot (0..7)
  int half = wv & 1;

  float acc[8][8] = {};

  // stage one kc=32 chunk into buffer `buf` (all 4 waves participate)
  auto stage = [&](int buf, int kb) {
    if (wv < 2) {
#pragma unroll
      for (int L = 0; L < 8; ++L) {
        int row = half * 64 + L * 8 + srow;
        int chunk = cp ^ ((row >> 3) & 7);
        gload16(A + row * 512 + kb + chunk * 4,
                &a_s[buf][(half * 64 + L * 8) * 32]);
      }
    } else {
#pragma unroll
      for (int L = 0; L < 8; ++L) {
        int row = half * 64 + L * 8 + srow;
        int chunk = cp ^ ((row >> 3) & 7);
        gload16(B + row * 512 + kb + chunk * 4,
                &b_s[buf][(half * 64 + L * 8) * 32]);
      }
    }
  };

  int aswz = ty & 7, bswz = tx & 7;
  const int aBase = ty * 8 * 32, bBase = tx * 8 * 32;

  stage(0, 0);
  __syncthreads();
#pragma unroll 1
  for (int c = 0; c < 16; ++c) {
    if (c < 15) stage((c + 1) & 1, (c + 1) * 32);
    const float* As = &a_s[c & 1][aBase];
    const float* Bs = &b_s[c & 1][bBase];
#pragma unroll
    for (int d4 = 0; d4 < 8; ++d4) {
      float4 av[8], bv[8];
#pragma unroll
      for (int p = 0; p < 8; ++p)
        av[p] = *(const float4*)(As + p * 32 + ((d4 ^ aswz) << 2));
#pragma unroll
      for (int q = 0; q < 8; ++q)
        bv[q] = *(const float4*)(Bs + q * 32 + ((d4 ^ bswz) << 2));
#pragma unroll
      for (int p = 0; p < 8; ++p)
#pragma unroll
        for (int q = 0; q < 8; ++q) {
          DOT4(acc[p][q], av[p], bv[q])
        }
    }
    __syncthreads();
  }

  float* Crow = sims + (bm * 128 + ty * 8) * 3200 + bn * 128 + tx * 8;
#pragma unroll
  for (int p = 0; p < 8; ++p) {
    *(float4*)(Crow + p * 3200) =
        make_float4(acc[p][0], acc[p][1], acc[p][2], acc[p][3]);
    *(float4*)(Crow + p * 3200 + 4) =
        make_float4(acc[p][4], acc[p][5], acc[p][6], acc[p][7]);
  }
}

// ---------------------------------------------------------------------------
// Kernel 4: attention epilogue. Block per (i,j), wave per 9 rows.
// G row cached in 50 VGPRs/lane; p broadcast via v_readlane (zero-LDS qform).
// ---------------------------------------------------------------------------
__global__ __launch_bounds__(256) void k_attn(
    const float* __restrict__ sims, const float* __restrict__ G,
    const float* __restrict__ unc, const float* __restrict__ nrm,
    const int* __restrict__ img_lens, const int* __restrict__ cap_lens,
    float* __restrict__ out) {
  __shared__ float g_s[64 * 51];
  int bid = blockIdx.x;
  int i = bid >> 6, j = bid & 63;
  int t = threadIdx.x, lane = t & 63, wv = t >> 6;

  for (int q = t; q < 2500; q += 256) {
    int w = q / 50, k = q - w * 50;
    g_s[w * 51 + k] = G[j * 2500 + q];
  }
  // zero pad rows 50..63 (lanes >= 50 read them; avoid NaN garbage)
  for (int q = t; q < 14 * 51; q += 256) g_s[50 * 51 + q] = 0.f;
  __syncthreads();

  float greg[50];
#pragma unroll
  for (int k = 0; k < 50; ++k) greg[k] = g_s[lane * 51 + k];

  int ilen = img_lens[i];
  int cl = cap_lens[j];
  cl = cl > 50 ? 50 : cl;
  const float* srow_base = sims + (i * 36) * 3200 + j * 50;

#pragma unroll 1
  for (int k9 = 0; k9 < 9; ++k9) {
    int r = wv * 9 + k9;
    float s = (lane < 50) ? srow_base[r * 3200 + lane] : 0.f;
    bool valid = lane < cl;
    float sv = valid ? s : -INFINITY;
    float m = wmax(sv);
    unsigned long long bal = __ballot(valid && (sv == m));
    int fl = (int)__ffsll((unsigned long long)bal) - 1;
    float e = valid ? __expf((sv - m) * TEMP_INV) : 0.f;
    float dn = wsum(e);
    float alpha = unc[i * 36 + r];
    float p = alpha * e / dn;
    if (m > MASKV && lane == fl) p += (1.f - alpha);
    float num = wsum(p * s);
    float gp = 0.f;
#pragma unroll
    for (int wp = 0; wp < 50; ++wp) {
      float pw = __uint_as_float(
          __builtin_amdgcn_readlane(__float_as_uint(p), wp));
      gp = fmaf(pw, greg[wp], gp);
    }
    float qd = wsum(p * gp);
    if (lane == 0) {
      float res = MASKV;
      if (r < ilen) {
        float ni = fmaxf(nrm[i * 36 + r], EPSV);
        float nw = fmaxf(sqrtf(qd), EPSV);
        res = num / (ni * nw);
      }
      out[(i * 64 + j) * 36 + r] = res;
    }
  }
}

extern "C" void kernel_launch(void* const* d_in, const int* in_sizes, int n_in,
                              void* d_out, int out_size, void* d_ws,
                              size_t ws_size, hipStream_t stream) {
  const float* imgs = (const float*)d_in[0];
  const float* caps = (const float*)d_in[1];
  const int* img_lens = (const int*)d_in[2];
  const int* cap_lens = (const int*)d_in[3];
  const float* W1 = (const float*)d_in[4];
  const float* b1 = (const float*)d_in[5];
  const float* W2 = (const float*)d_in[6];
  const float* b2 = (const float*)d_in[7];
  float* out = (float*)d_out;
  float* ws = (float*)d_ws;
  float* unc = ws;               // 2304 floats
  float* nrm = ws + 2304;        // 2304 floats
  float* G = ws + 4608;          // 160000 floats
  float* sims = ws + 164608;     // 7,372,800 floats (29.5 MB)

  hipLaunchKernelGGL(k_prep, dim3(9, 64), dim3(256), 0, stream, imgs, W1, b1,
                     W2, b2, unc, nrm);
  hipLaunchKernelGGL(k_gram, dim3(2, 64), dim3(128), 0, stream, caps, G);
  hipLaunchKernelGGL(k_sims, dim3(450), dim3(256), 0, stream, imgs, caps,
                     sims);
  hipLaunchKernelGGL(k_attn, dim3(4096), dim3(256), 0, stream, sims, G, unc,
                     nrm, img_lens, cap_lens, out);
}

// Round 5
// 238.443 us; speedup vs baseline: 3.1718x; 1.2932x over previous
//
#include <hip/hip_runtime.h>
#include <math.h>

#define TEMP_INV 10.0f
#define MASKV -1.0f
#define EPSV 1e-12f
#define GAP 2e-3f

typedef __attribute__((ext_vector_type(8))) short bf16x8;
typedef __attribute__((ext_vector_type(4))) float f32x4;

__device__ __forceinline__ float wmax(float v) {
#pragma unroll
  for (int m = 1; m < 64; m <<= 1) v = fmaxf(v, __shfl_xor(v, m));
  return v;
}
__device__ __forceinline__ float wsum(float v) {
#pragma unroll
  for (int m = 1; m < 64; m <<= 1) v += __shfl_xor(v, m);
  return v;
}

__device__ __forceinline__ unsigned short rne_bf16(float x) {
  unsigned u = __float_as_uint(x);
  return (unsigned short)((u + 0x7FFF + ((u >> 16) & 1)) >> 16);
}

#define DOT4(accv, Av, Bv)       \
  accv = fmaf(Av.x, Bv.x, accv); \
  accv = fmaf(Av.y, Bv.y, accv); \
  accv = fmaf(Av.z, Bv.z, accv); \
  accv = fmaf(Av.w, Bv.w, accv);

// ---------------------------------------------------------------------------
// Kernel 1: h = relu(imgs@W1+b1); unc = sigmoid(h@W2+b2); img row norms
// ---------------------------------------------------------------------------
__global__ __launch_bounds__(256) void k_prep(
    const float* __restrict__ imgs, const float* __restrict__ W1,
    const float* __restrict__ b1, const float* __restrict__ W2,
    const float* __restrict__ b2, float* __restrict__ unc,
    float* __restrict__ nrm) {
  int i = blockIdx.y;
  int r0 = blockIdx.x * 4;
  int t = threadIdx.x, lane = t & 63, wv = t >> 6;
  __shared__ __align__(16) float im[4][512];
  __shared__ float part[8][4];

  for (int q = t; q < 512; q += 256) {
    int rr = q >> 7;
    int dq = (q & 127) << 2;
    *(float4*)&im[rr][dq] = *(const float4*)&imgs[(i * 36 + r0 + rr) * 512 + dq];
  }
  __syncthreads();

  float a0 = 0.f, a1 = 0.f, a2 = 0.f, a3 = 0.f;
  for (int d = 0; d < 512; ++d) {
    float w = W1[d * 256 + t];
    a0 = fmaf(im[0][d], w, a0);
    a1 = fmaf(im[1][d], w, a1);
    a2 = fmaf(im[2][d], w, a2);
    a3 = fmaf(im[3][d], w, a3);
  }
  float bb = b1[t], w2 = W2[t];
  float v[4];
  v[0] = fmaxf(a0 + bb, 0.f) * w2;
  v[1] = fmaxf(a1 + bb, 0.f) * w2;
  v[2] = fmaxf(a2 + bb, 0.f) * w2;
  v[3] = fmaxf(a3 + bb, 0.f) * w2;
  float n[4];
#pragma unroll
  for (int p = 0; p < 4; ++p) {
    float x0 = im[p][t], x1 = im[p][t + 256];
    n[p] = x0 * x0 + x1 * x1;
  }
#pragma unroll
  for (int m = 1; m < 64; m <<= 1) {
#pragma unroll
    for (int p = 0; p < 4; ++p) {
      v[p] += __shfl_xor(v[p], m);
      n[p] += __shfl_xor(n[p], m);
    }
  }
  if (lane == 0) {
#pragma unroll
    for (int p = 0; p < 4; ++p) {
      part[p][wv] = v[p];
      part[4 + p][wv] = n[p];
    }
  }
  __syncthreads();
  if (t < 8) {
    float s = part[t][0] + part[t][1] + part[t][2] + part[t][3];
    if (t < 4)
      unc[i * 36 + r0 + t] = 1.f / (1.f + __expf(-(s + b2[0])));
    else
      nrm[i * 36 + r0 + (t - 4)] = sqrtf(s);
  }
}

// ---------------------------------------------------------------------------
// Kernel 2: Gram matrices G[j][w][w'] = caps[j,w].caps[j,w'] (row-major 50)
// ---------------------------------------------------------------------------
__global__ __launch_bounds__(128) void k_gram(const float* __restrict__ caps,
                                              float* __restrict__ G) {
  int j = blockIdx.y, h = blockIdx.x;
  int t = threadIdx.x;
  __shared__ __align__(16) float cs[52 * 128];

  int rg = t / 13, wg = t - rg * 13;
  bool act = (t < 91);
  int r0 = h * 24 + 4 * rg;
  int w0 = 4 * wg;
  int fa = (r0 >> 2) & 7;
  int fb = wg & 7;
  float acc[4][4] = {};

  for (int ch = 0; ch < 4; ++ch) {
    int d0 = ch * 128;
    for (int ps = 0; ps < 13; ++ps) {
      int row = ps * 4 + (t >> 5);
      int c = t & 31;
      int grow = row > 49 ? 49 : row;
      float4 v = *(const float4*)&caps[(j * 50 + grow) * 512 + d0 + c * 4];
      *(float4*)&cs[row * 128 + ((c ^ (ps & 7)) << 2)] = v;
    }
    __syncthreads();
    if (act) {
      const float* aB = &cs[r0 * 128];
      const float* bB = &cs[w0 * 128];
#pragma unroll
      for (int q = 0; q < 32; ++q) {
        int pa = ((q ^ fa) << 2), pb = ((q ^ fb) << 2);
        float4 A0 = *(const float4*)(aB + pa);
        float4 A1 = *(const float4*)(aB + 128 + pa);
        float4 A2 = *(const float4*)(aB + 256 + pa);
        float4 A3 = *(const float4*)(aB + 384 + pa);
        float4 B0 = *(const float4*)(bB + pb);
        float4 B1 = *(const float4*)(bB + 128 + pb);
        float4 B2 = *(const float4*)(bB + 256 + pb);
        float4 B3 = *(const float4*)(bB + 384 + pb);
        DOT4(acc[0][0], A0, B0) DOT4(acc[0][1], A0, B1)
        DOT4(acc[0][2], A0, B2) DOT4(acc[0][3], A0, B3)
        DOT4(acc[1][0], A1, B0) DOT4(acc[1][1], A1, B1)
        DOT4(acc[1][2], A1, B2) DOT4(acc[1][3], A1, B3)
        DOT4(acc[2][0], A2, B0) DOT4(acc[2][1], A2, B1)
        DOT4(acc[2][2], A2, B2) DOT4(acc[2][3], A2, B3)
        DOT4(acc[3][0], A3, B0) DOT4(acc[3][1], A3, B1)
        DOT4(acc[3][2], A3, B2) DOT4(acc[3][3], A3, B3)
      }
    }
    __syncthreads();
  }
  if (act) {
#pragma unroll
    for (int p = 0; p < 4; ++p) {
      int w = r0 + p;
      if (w < 50) {
#pragma unroll
        for (int qq = 0; qq < 4; ++qq) {
          int wp = w0 + qq;
          if (wp < 50) G[j * 2500 + w * 50 + wp] = acc[p][qq];
        }
      }
    }
  }
}

// ---------------------------------------------------------------------------
// Kernel 3: sims via MFMA bf16x3 split GEMM.
// C[2304][3200] = imgs · capsᵀ, K=512. Block 128×128, 4 waves (2×2 of 64×64),
// wave = 4×4 of 16×16×32 mfma tiles. Per K64 chunk: reg-stage fp32 → hi/lo
// bf16 into K-major LDS tiles [128 rows][64 bf16] with slot-XOR swizzle
// s^(row&7). 3-term accumulate: ah·bh + ah·bl + al·bh.
// ---------------------------------------------------------------------------
__global__ __launch_bounds__(256, 2) void k_sims(const float* __restrict__ imgs,
                                                 const float* __restrict__ caps,
                                                 float* __restrict__ sims) {
  __shared__ __align__(16) short AH[128 * 64];
  __shared__ __align__(16) short AL[128 * 64];
  __shared__ __align__(16) short BH[128 * 64];
  __shared__ __align__(16) short BL[128 * 64];

  int bid = blockIdx.x;
  int bm = bid / 25, bn = bid - bm * 25;
  int t = threadIdx.x, lane = t & 63, wv = t >> 6;

  int wm = wv >> 1, wn = wv & 1;
  int frow = lane & 15, fk = lane >> 4;
  int sw = frow & 7;

  // staging: iter ii 0..3 -> row = ii*32 + (t>>3), slot q = t&7 (8 f32)
  int srow = t >> 3, sq = t & 7;
  const float* aBase = imgs + (size_t)(bm * 128 + srow) * 512 + 8 * sq;
  const float* bBase = caps + (size_t)(bn * 128 + srow) * 512 + 8 * sq;

  f32x4 acc[4][4] = {};

  for (int kc = 0; kc < 8; ++kc) {
    // ---- stage chunk kc ----
#pragma unroll
    for (int ii = 0; ii < 4; ++ii) {
      int row = ii * 32 + srow;
      int sp = ((sq ^ (row & 7)) << 3) + row * 64;
      {
        const float* p = aBase + (size_t)(ii * 32) * 512 + kc * 64;
        float4 x0 = *(const float4*)p;
        float4 x1 = *(const float4*)(p + 4);
        float xs[8] = {x0.x, x0.y, x0.z, x0.w, x1.x, x1.y, x1.z, x1.w};
        bf16x8 hi, lo;
#pragma unroll
        for (int e = 0; e < 8; ++e) {
          unsigned short hb = rne_bf16(xs[e]);
          float hf = __uint_as_float((unsigned)hb << 16);
          hi[e] = (short)hb;
          lo[e] = (short)rne_bf16(xs[e] - hf);
        }
        *(bf16x8*)&AH[sp] = hi;
        *(bf16x8*)&AL[sp] = lo;
      }
      {
        const float* p = bBase + (size_t)(ii * 32) * 512 + kc * 64;
        float4 x0 = *(const float4*)p;
        float4 x1 = *(const float4*)(p + 4);
        float xs[8] = {x0.x, x0.y, x0.z, x0.w, x1.x, x1.y, x1.z, x1.w};
        bf16x8 hi, lo;
#pragma unroll
        for (int e = 0; e < 8; ++e) {
          unsigned short hb = rne_bf16(xs[e]);
          float hf = __uint_as_float((unsigned)hb << 16);
          hi[e] = (short)hb;
          lo[e] = (short)rne_bf16(xs[e] - hf);
        }
        *(bf16x8*)&BH[sp] = hi;
        *(bf16x8*)&BL[sp] = lo;
      }
    }
    __syncthreads();

    // ---- compute: 2 K32-steps ----
#pragma unroll
    for (int ks = 0; ks < 2; ++ks) {
      int slot = (ks << 2) | fk;
      bf16x8 bh[4], bl[4];
#pragma unroll
      for (int nt = 0; nt < 4; ++nt) {
        int br = wn * 64 + nt * 16 + frow;
        int off = br * 64 + ((slot ^ sw) << 3);
        bh[nt] = *(const bf16x8*)&BH[off];
        bl[nt] = *(const bf16x8*)&BL[off];
      }
#pragma unroll
      for (int mt = 0; mt < 4; ++mt) {
        int ar = wm * 64 + mt * 16 + frow;
        int off = ar * 64 + ((slot ^ sw) << 3);
        bf16x8 ah = *(const bf16x8*)&AH[off];
        bf16x8 al = *(const bf16x8*)&AL[off];
#pragma unroll
        for (int nt = 0; nt < 4; ++nt) {
          acc[mt][nt] = __builtin_amdgcn_mfma_f32_16x16x32_bf16(
              ah, bh[nt], acc[mt][nt], 0, 0, 0);
          acc[mt][nt] = __builtin_amdgcn_mfma_f32_16x16x32_bf16(
              ah, bl[nt], acc[mt][nt], 0, 0, 0);
          acc[mt][nt] = __builtin_amdgcn_mfma_f32_16x16x32_bf16(
              al, bh[nt], acc[mt][nt], 0, 0, 0);
        }
      }
    }
    __syncthreads();
  }

  // ---- epilogue: C/D layout col = lane&15, row = 4*(lane>>4)+reg ----
#pragma unroll
  for (int mt = 0; mt < 4; ++mt) {
#pragma unroll
    for (int nt = 0; nt < 4; ++nt) {
      int grow0 = bm * 128 + wm * 64 + mt * 16 + fk * 4;
      int gcol = bn * 128 + wn * 64 + nt * 16 + frow;
#pragma unroll
      for (int v = 0; v < 4; ++v)
        sims[(size_t)(grow0 + v) * 3200 + gcol] = acc[mt][nt][v];
    }
  }
}

// ---------------------------------------------------------------------------
// Kernel 4: attention epilogue. Block per (i,j), wave per 9 rows.
// Argmax from approx sims with GAP-ballot; exact fp32 recompute fallback for
// ambiguous rows. Quadratic form pᵀGp via readlane, 4 accumulators.
// ---------------------------------------------------------------------------
__global__ __launch_bounds__(256) void k_attn(
    const float* __restrict__ sims, const float* __restrict__ G,
    const float* __restrict__ unc, const float* __restrict__ nrm,
    const int* __restrict__ img_lens, const int* __restrict__ cap_lens,
    const float* __restrict__ imgs, const float* __restrict__ caps,
    float* __restrict__ out) {
  __shared__ float g_s[64 * 51];
  int bid = blockIdx.x;
  int i = bid >> 6, j = bid & 63;
  int t = threadIdx.x, lane = t & 63, wv = t >> 6;

  for (int q = t; q < 2500; q += 256) {
    int w = q / 50, k = q - w * 50;
    g_s[w * 51 + k] = G[j * 2500 + q];
  }
  for (int q = t; q < 14 * 51; q += 256) g_s[50 * 51 + q] = 0.f;
  __syncthreads();

  float greg[50];
#pragma unroll
  for (int k = 0; k < 50; ++k) greg[k] = g_s[lane * 51 + k];

  int ilen = img_lens[i];
  int cl = cap_lens[j];
  cl = cl > 50 ? 50 : cl;
  const float* srow_base = sims + (size_t)(i * 36) * 3200 + j * 50;

#pragma unroll 1
  for (int k9 = 0; k9 < 9; ++k9) {
    int r = wv * 9 + k9;
    float s = (lane < 50) ? srow_base[(size_t)r * 3200 + lane] : 0.f;
    bool valid = lane < cl;
    float sv = valid ? s : -INFINITY;
    float m = wmax(sv);
    bool cand = valid && (sv >= m - GAP);
    unsigned long long nearmask = __ballot(cand);
    int fl;
    if (__popcll(nearmask) <= 1) {
      fl = (int)__ffsll(nearmask) - 1;
    } else {
      // exact fp32 recompute on candidate lanes (rare)
      float ex = -INFINITY;
      if (cand) {
        const float* ar = imgs + (size_t)(i * 36 + r) * 512;
        const float* br = caps + (size_t)(j * 50 + lane) * 512;
        float4 a4 = make_float4(0.f, 0.f, 0.f, 0.f);
        for (int k = 0; k < 512; k += 4) {
          float4 av = *(const float4*)(ar + k);
          float4 bv = *(const float4*)(br + k);
          a4.x = fmaf(av.x, bv.x, a4.x);
          a4.y = fmaf(av.y, bv.y, a4.y);
          a4.z = fmaf(av.z, bv.z, a4.z);
          a4.w = fmaf(av.w, bv.w, a4.w);
        }
        ex = (a4.x + a4.y) + (a4.z + a4.w);
      }
      float mex = wmax(ex);
      fl = (int)__ffsll(__ballot(ex == mex)) - 1;
    }
    float e = valid ? __expf((sv - m) * TEMP_INV) : 0.f;
    float dn = wsum(e);
    float alpha = unc[i * 36 + r];
    float p = alpha * e / dn;
    if (m > MASKV && lane == fl) p += (1.f - alpha);
    float num = wsum(valid ? p * s : 0.f);
    // gp(lane) = (G p)[lane], 4 accumulators to break the fma chain
    float gp0 = 0.f, gp1 = 0.f, gp2 = 0.f, gp3 = 0.f;
#pragma unroll
    for (int wp = 0; wp < 48; wp += 4) {
      gp0 = fmaf(__uint_as_float(__builtin_amdgcn_readlane(__float_as_uint(p), wp)), greg[wp], gp0);
      gp1 = fmaf(__uint_as_float(__builtin_amdgcn_readlane(__float_as_uint(p), wp + 1)), greg[wp + 1], gp1);
      gp2 = fmaf(__uint_as_float(__builtin_amdgcn_readlane(__float_as_uint(p), wp + 2)), greg[wp + 2], gp2);
      gp3 = fmaf(__uint_as_float(__builtin_amdgcn_readlane(__float_as_uint(p), wp + 3)), greg[wp + 3], gp3);
    }
    gp0 = fmaf(__uint_as_float(__builtin_amdgcn_readlane(__float_as_uint(p), 48)), greg[48], gp0);
    gp1 = fmaf(__uint_as_float(__builtin_amdgcn_readlane(__float_as_uint(p), 49)), greg[49], gp1);
    float gp = (gp0 + gp1) + (gp2 + gp3);
    float qd = wsum(p * gp);
    if (lane == 0) {
      float res = MASKV;
      if (r < ilen) {
        float ni = fmaxf(nrm[i * 36 + r], EPSV);
        float nw = fmaxf(sqrtf(qd), EPSV);
        res = num / (ni * nw);
      }
      out[(i * 64 + j) * 36 + r] = res;
    }
  }
}

extern "C" void kernel_launch(void* const* d_in, const int* in_sizes, int n_in,
                              void* d_out, int out_size, void* d_ws,
                              size_t ws_size, hipStream_t stream) {
  const float* imgs = (const float*)d_in[0];
  const float* caps = (const float*)d_in[1];
  const int* img_lens = (const int*)d_in[2];
  const int* cap_lens = (const int*)d_in[3];
  const float* W1 = (const float*)d_in[4];
  const float* b1 = (const float*)d_in[5];
  const float* W2 = (const float*)d_in[6];
  const float* b2 = (const float*)d_in[7];
  float* out = (float*)d_out;
  float* ws = (float*)d_ws;
  float* unc = ws;            // 2304 floats
  float* nrm = ws + 2304;     // 2304 floats
  float* G = ws + 4608;       // 160000 floats
  float* sims = ws + 164608;  // 7,372,800 floats (29.5 MB)

  hipLaunchKernelGGL(k_prep, dim3(9, 64), dim3(256), 0, stream, imgs, W1, b1,
                     W2, b2, unc, nrm);
  hipLaunchKernelGGL(k_gram, dim3(2, 64), dim3(128), 0, stream, caps, G);
  hipLaunchKernelGGL(k_sims, dim3(450), dim3(256), 0, stream, imgs, caps,
                     sims);
  hipLaunchKernelGGL(k_attn, dim3(4096), dim3(256), 0, stream, sims, G, unc,
                     nrm, img_lens, cap_lens, imgs, caps, out);
}